// Round 6
// baseline (426.768 us; speedup 1.0000x reference)
//
#include <hip/hip_runtime.h>

#define B_SZ 16
#define N_SZ 8192
#define D_SZ 384
#define KN_SZ 16
#define K_SZ 8
#define H_SZ 128
#define M_TOTAL (B_SZ * N_SZ)   // 131072 nodes
#define KSTEPS 12               // 384 / 32
#define MT64 (M_TOTAL / 64)     // 2048 64-row tiles
#define HS_STRIDE 130           // f32 elems/row for hs (odd dw stride: conflict-free)

typedef short short8 __attribute__((ext_vector_type(8)));
typedef float floatx4 __attribute__((ext_vector_type(4)));

__device__ __forceinline__ unsigned short f2bf(float f) {
    unsigned u = __builtin_bit_cast(unsigned, f);
    u += 0x7FFFu + ((u >> 16) & 1u);   // round-to-nearest-even
    return (unsigned short)(u >> 16);
}
__device__ __forceinline__ float bf2f(unsigned short b) {
    unsigned u = ((unsigned)b) << 16;
    return __builtin_bit_cast(float, u);
}
// HW packed f32->bf16 (RNE), 2 elems / inst
__device__ __forceinline__ unsigned pkbf(float a, float b) {
    unsigned r;
    asm("v_cvt_pk_bf16_f32 %0, %1, %2" : "=v"(r) : "v"(a), "v"(b));
    return r;
}
// 8 f32 -> short8 bf16 (same pair order as the old LDS staging path)
__device__ __forceinline__ short8 cvt8(float4 lo, float4 hi) {
    union { int4 i; short8 s; } u;
    u.i.x = (int)pkbf(lo.x, lo.y);
    u.i.y = (int)pkbf(lo.z, lo.w);
    u.i.z = (int)pkbf(hi.x, hi.y);
    u.i.w = (int)pkbf(hi.z, hi.w);
    return u.s;
}

// ---------------------------------------------------------------------------
// PREP: blocks 0..383 build swizzled fused weights; block 384 zeroes norms;
// blocks 385..400 per-batch q contributions (+layer-1 biases), exact fp32.
// wswz: flat = ((ct*12+s)*64 + lane)*8 + j <-> B[k=s*32+(lane>>4)*8+j][n=ct*16+(lane&15)]
// ---------------------------------------------------------------------------
__global__ void prep_kernel(const float* __restrict__ q_embs,
                            const float* __restrict__ coin_w1,
                            const float* __restrict__ coin_b1,
                            const float* __restrict__ path_w1,
                            const float* __restrict__ path_b1,
                            unsigned short* __restrict__ wswz,
                            float* __restrict__ qcoin, float* __restrict__ qpath,
                            float* __restrict__ norms) {
    int blk = blockIdx.x;
    int t = threadIdx.x;
    if (blk < 384) {
        int f = blk * 256 + t;                   // 98304 total
        int j  = f & 7;
        int l  = (f >> 3) & 63;
        int ss = (f >> 9) % KSTEPS;
        int ct = f / (KSTEPS * 512);
        int k = ss * 32 + ((l >> 4) << 3) + j;
        int n = ct * 16 + (l & 15);
        float v = (n < H_SZ) ? coin_w1[k * H_SZ + n]
                             : path_w1[k * H_SZ + (n - H_SZ)];
        wswz[f] = f2bf(v);
    } else if (blk == 384) {
        if (t < B_SZ) norms[t] = 0.f;
    } else {
        int b = blk - 385;
        const float* q = q_embs + b * D_SZ;
        if (t < H_SZ) {
            float acc = coin_b1[t];
            for (int d = 0; d < D_SZ; d++)
                acc += q[d] * coin_w1[(D_SZ + d) * H_SZ + t];
            qcoin[b * H_SZ + t] = acc;
        } else if (t < 2 * H_SZ) {
            int h = t - H_SZ;
            float acc = path_b1[h];
            for (int d = 0; d < D_SZ; d++)
                acc += q[d] * path_w1[(D_SZ + K_SZ + d) * H_SZ + h];
            qpath[b * H_SZ + h] = acc;
        }
    }
}

// ---------------------------------------------------------------------------
// GEMM v8: LDS-free K-loop. Each lane loads its MFMA A-fragments DIRECTLY
// from global (2 x float4 per fragment; per wave-instr: 16 rows x one aligned
// 128B line each, fully consumed) and converts f32->bf16 in registers.
// Per s, the 64-row working set is 8 KB -> L1-resident for the 4 waves.
// No barriers until the amps epilogue. B streamed from L2-resident wswz.
// ---------------------------------------------------------------------------
__global__ __launch_bounds__(256)
void gemm_fused(const float* __restrict__ sent,
                const unsigned short* __restrict__ wswz,
                const float* __restrict__ qcoin,
                const float* __restrict__ coin_w2,
                const float* __restrict__ coin_b2,
                unsigned short* __restrict__ hpathB,
                float* __restrict__ amps) {
    __shared__ float hs[64 * HS_STRIDE];         // 33280 B
    __shared__ float w2s[H_SZ * K_SZ];           // 4096 B  (37376 total -> 4 blk/CU)
    const int tid = threadIdx.x;
    const int wave = tid >> 6, lane = tid & 63;
    const int m_lane = lane & 15, quad = lane >> 4;
    const int mt = blockIdx.x;                   // 2048 blocks, one tile each
    const int b = mt >> 7;                       // batch (8192 rows / batch)

    // w2s staging overlaps the K-loop (ordered by the epilogue barrier)
    for (int i = tid; i < H_SZ * K_SZ; i += 256) w2s[i] = coin_w2[i];

    // lane's fragment base: row = rt*16 + m_lane, col = s*32 + quad*8
    const float* aF = sent + (size_t)mt * 64 * D_SZ + (size_t)m_lane * D_SZ + quad * 8;
    const unsigned short* wbase = wswz + (size_t)wave * 4 * KSTEPS * 512 + lane * 8;

    floatx4 acc[4][4];
#pragma unroll
    for (int rt = 0; rt < 4; rt++)
#pragma unroll
        for (int c = 0; c < 4; c++) acc[rt][c] = (floatx4){0.f, 0.f, 0.f, 0.f};

    float4 ca[4], cb[4];
#define LOADA(S)                                                                 \
    _Pragma("unroll")                                                            \
    for (int rt = 0; rt < 4; rt++) {                                             \
        const float* p = aF + (size_t)rt * 16 * D_SZ + (S) * 32;                 \
        ca[rt] = *(const float4*)p;                                              \
        cb[rt] = *(const float4*)(p + 4);                                        \
    }

    LOADA(0);
#pragma unroll 1
    for (int s = 0; s < KSTEPS; s++) {
        short8 bfr[4];
#pragma unroll
        for (int cc = 0; cc < 4; cc++)
            bfr[cc] = *(const short8*)(wbase + (size_t)(cc * KSTEPS + s) * 512);
        short8 af[4];
#pragma unroll
        for (int rt = 0; rt < 4; rt++) af[rt] = cvt8(ca[rt], cb[rt]);
        if (s + 1 < KSTEPS) { LOADA(s + 1); }    // prefetch flies under the MFMAs
#pragma unroll
        for (int rt = 0; rt < 4; rt++)
#pragma unroll
            for (int cc = 0; cc < 4; cc++)
                acc[rt][cc] = __builtin_amdgcn_mfma_f32_16x16x32_bf16(
                    af[rt], bfr[cc], acc[rt][cc], 0, 0, 0);
    }
#undef LOADA

    // ---- epilogue A: path waves store blocked int2 bf16 h (register-only) ----
    if (wave >= 2) {
        const int colw = (wave & 1) * 64;
#pragma unroll
        for (int rt = 0; rt < 4; rt++) {
            int mt16 = mt * 4 + rt;
#pragma unroll
            for (int c = 0; c < 4; c++) {
                int col = colw + c * 16 + m_lane;
                int2 p;
                p.x = (int)pkbf(acc[rt][c][0], acc[rt][c][1]);
                p.y = (int)pkbf(acc[rt][c][2], acc[rt][c][3]);
                *(int2*)(hpathB + (size_t)mt16 * 2048 + col * 16 + quad * 4) = p;
            }
        }
    }

    // ---- epilogue B: coin waves -> relu(h + qcoin) into LDS (f32) ----
    if (wave < 2) {
        const int colw = wave * 64;
        float qc[4];
#pragma unroll
        for (int c = 0; c < 4; c++)
            qc[c] = qcoin[b * H_SZ + colw + c * 16 + m_lane];
#pragma unroll
        for (int rt = 0; rt < 4; rt++)
#pragma unroll
            for (int c = 0; c < 4; c++) {
                int colj = colw + c * 16 + m_lane;
#pragma unroll
                for (int j = 0; j < 4; j++) {
                    int row = rt * 16 + quad * 4 + j;
                    float hv = acc[rt][c][j] + qc[c];
                    hs[row * HS_STRIDE + colj] = hv > 0.f ? hv : 0.f;
                }
            }
    }
    __syncthreads();                             // the kernel's only barrier

    // ---- epilogue C: amps[m][k] = hs_row @ w2 + b2 ----
    {
        const int r = tid >> 2;                  // 0..63 row in tile
        const int kk = (tid & 3) * 2;            // k pair
        float a0 = coin_b2[kk], a1 = coin_b2[kk + 1];
#pragma unroll 8
        for (int c = 0; c < H_SZ; c++) {
            float hv = hs[r * HS_STRIDE + c];
            float2 w = *(const float2*)&w2s[c * 8 + kk];
            a0 += hv * w.x; a1 += hv * w.y;
        }
        const size_t m = (size_t)mt * 64 + r;
        *(float2*)(amps + m * 8 + kk) = make_float2(a0, a1);
    }
}

// ---------------------------------------------------------------------------
// walk_fused: one block per (batch b, coin k) slice — 128 blocks x 1024 thr.
// Slice state (8192 f32 = 32 KB) double-buffered in LDS; all 3 steps with
// plain __syncthreads(). amps in registers; z never round-trips HBM.
// ---------------------------------------------------------------------------
__global__ __launch_bounds__(1024)
void walk_fused(const float* __restrict__ amps,
                const int* __restrict__ neighbors,
                float* __restrict__ zfinal,
                float* __restrict__ norms) {
    __shared__ float z0buf[N_SZ];    // 32 KB
    __shared__ float z1buf[N_SZ];    // 32 KB
    __shared__ float bsum;
    const int tid = threadIdx.x;
    const int b = blockIdx.x >> 3;
    const int k = blockIdx.x & 7;
    const size_t nodebase = (size_t)b * N_SZ;

    float a[8];
#pragma unroll
    for (int u = 0; u < 8; u++) {
        int n = u * 1024 + tid;
        a[u] = amps[(nodebase + n) * 8 + k];
        z0buf[n] = a[u] * (1.0f / 256.0f);       // exact pow2 fold of z0
    }
    if (tid == 0) bsum = 0.f;
    __syncthreads();

    float* zc = z0buf;
    float* zn = z1buf;
    float ss = 0.f;
#pragma unroll
    for (int step = 0; step < 3; step++) {
#pragma unroll
        for (int u = 0; u < 8; u++) {
            const int n = u * 1024 + tid;
            const int4* nb4 = (const int4*)(neighbors + (nodebase + n) * KN_SZ);
            int4 q0 = nb4[0], q1 = nb4[1], q2 = nb4[2], q3 = nb4[3];
            float v = zc[n];
            int idx[16] = {q0.x, q0.y, q0.z, q0.w, q1.x, q1.y, q1.z, q1.w,
                           q2.x, q2.y, q2.z, q2.w, q3.x, q3.y, q3.z, q3.w};
#pragma unroll
            for (int i = 0; i < 16; i++) {
                int nn = idx[i];
                if ((unsigned)nn < (unsigned)N_SZ) v += zc[nn];
            }
            if (step < 2) v *= a[u];
            zn[n] = v;
            if (step == 2) ss += v * v;
        }
        __syncthreads();
        float* t = zc; zc = zn; zn = t;
    }

#pragma unroll
    for (int o = 32; o > 0; o >>= 1) ss += __shfl_down(ss, o);
    if ((tid & 63) == 0) atomicAdd(&bsum, ss);
    __syncthreads();
    if (tid == 0) atomicAdd(&norms[b], bsum);

#pragma unroll
    for (int u = 0; u < 8; u++) {
        int n = u * 1024 + tid;
        zfinal[(nodebase + n) * 8 + k] = zc[n];
    }
}

// ---------------------------------------------------------------------------
// logits v3: 4 threads per node (seg = tid&3 owns 32 h's), reads the BLOCKED
// hpathB layout coalesced. Seg-padded LDS weight layouts conflict-free.
// ---------------------------------------------------------------------------
__global__ __launch_bounds__(256)
void logits_kernel(const unsigned short* __restrict__ hpathB,
                   const float* __restrict__ qpath,
                   const float* __restrict__ u2,
                   const float* __restrict__ norms,
                   const float* __restrict__ path_w1,
                   const float* __restrict__ path_w2,
                   const float* __restrict__ path_b2,
                   float* __restrict__ out) {
    __shared__ float w1t[4 * 260];   // seg*260 + i*8 + j
    __shared__ float w2sp[4 * 33];   // seg*33 + i
    __shared__ float qps[4 * 33];
    const int tid = threadIdx.x;
    const int mbase = blockIdx.x * 64;           // 64 nodes / block, 2048 blocks
    const int b = mbase >> 13;                   // block-uniform (128 blocks/batch)
    for (int i2 = tid; i2 < H_SZ * K_SZ; i2 += 256) {
        int h = i2 >> 3, j = i2 & 7;
        w1t[(h >> 5) * 260 + (h & 31) * 8 + j] = path_w1[(D_SZ + j) * H_SZ + h];
    }
    if (tid < H_SZ) {
        int idx = (tid >> 5) * 33 + (tid & 31);
        w2sp[idx] = path_w2[tid];
        qps[idx]  = qpath[b * H_SZ + tid];
    }
    __syncthreads();

    const int m = mbase + (tid >> 2);
    const int seg = tid & 3;
    float ssq = norms[b];
    float inv = ssq > 0.f ? rsqrtf(ssq) : 1.0f;
    float st[K_SZ];
    {
        float4 s0 = *(const float4*)(u2 + (size_t)m * 8);
        float4 s1 = *(const float4*)(u2 + (size_t)m * 8 + 4);
        st[0] = s0.x * inv; st[1] = s0.y * inv; st[2] = s0.z * inv; st[3] = s0.w * inv;
        st[4] = s1.x * inv; st[5] = s1.y * inv; st[6] = s1.z * inv; st[7] = s1.w * inv;
    }
    const unsigned short* hb = hpathB + (size_t)(m >> 4) * 2048 + (m & 15);
    const float* w1b = &w1t[seg * 260];
    const float* w2b = &w2sp[seg * 33];
    const float* qpb = &qps[seg * 33];
    const int hseg = seg * 32;

    float acc = 0.f;
#pragma unroll 8
    for (int i = 0; i < 32; i++) {
        float hv = bf2f(hb[(hseg + i) * 16]) + qpb[i];
        float4 wa = *(const float4*)&w1b[i * 8];
        float4 wb = *(const float4*)&w1b[i * 8 + 4];
        hv += st[0]*wa.x + st[1]*wa.y + st[2]*wa.z + st[3]*wa.w
            + st[4]*wb.x + st[5]*wb.y + st[6]*wb.z + st[7]*wb.w;
        hv = hv > 0.f ? hv : 0.f;
        acc += hv * w2b[i];
    }
    acc += __shfl_xor(acc, 1);
    acc += __shfl_xor(acc, 2);
    if (seg == 0) out[m] = acc + path_b2[0];
}

// ---------------------------------------------------------------------------
extern "C" void kernel_launch(void* const* d_in, const int* in_sizes, int n_in,
                              void* d_out, int out_size, void* d_ws, size_t ws_size,
                              hipStream_t stream) {
    const float* sent      = (const float*)d_in[0];
    const float* q_embs    = (const float*)d_in[1];
    const int*   neighbors = (const int*)d_in[2];
    const float* coin_w1   = (const float*)d_in[3];
    const float* coin_b1   = (const float*)d_in[4];
    const float* coin_w2   = (const float*)d_in[5];
    const float* coin_b2   = (const float*)d_in[6];
    const float* path_w1   = (const float*)d_in[7];
    const float* path_b1   = (const float*)d_in[8];
    const float* path_w2   = (const float*)d_in[9];
    const float* path_b2   = (const float*)d_in[10];
    float* out = (float*)d_out;

    char* ws = (char*)d_ws;
    unsigned short* wswz = (unsigned short*)ws;                   // 196608 B
    float* qcoin = (float*)(ws + 196608);                         // 8192 B
    float* qpath = (float*)(ws + 204800);                         // 8192 B
    float* norms = (float*)(ws + 212992);                         // 256 B
    unsigned short* hpathB = (unsigned short*)(ws + 213248);      // 33554432 B
    float* amps = (float*)(ws + 33767680);                        // 4 MB
    float* zB   = (float*)(ws + 37961984);                        // 4 MB

    prep_kernel<<<401, 256, 0, stream>>>(q_embs, coin_w1, coin_b1, path_w1, path_b1,
                                         wswz, qcoin, qpath, norms);
    gemm_fused<<<MT64, 256, 0, stream>>>(sent, wswz, qcoin, coin_w2, coin_b2,
                                         hpathB, amps);
    walk_fused<<<B_SZ * K_SZ, 1024, 0, stream>>>(amps, neighbors, zB, norms);
    logits_kernel<<<M_TOTAL / 64, 256, 0, stream>>>(hpathB, qpath, zB, norms,
                                                    path_w1, path_w2, path_b2, out);
}

// Round 7
// 385.304 us; speedup vs baseline: 1.1076x; 1.1076x over previous
//
#include <hip/hip_runtime.h>

#define B_SZ 16
#define N_SZ 8192
#define D_SZ 384
#define KN_SZ 16
#define K_SZ 8
#define H_SZ 128
#define M_TOTAL (B_SZ * N_SZ)   // 131072 nodes
#define KSTEPS 12               // 384 / 32
#define MT64 (M_TOTAL / 64)     // 2048 64-row tiles
#define CK 128                  // K-chunk (3 chunks of 128)
#define LDSB_STRIDE 144         // bf16 elems/row; 72 dw == 8 mod 32 -> conflict-free b128
#define HS_STRIDE 130           // f32 elems/row for hs overlay

typedef short short8 __attribute__((ext_vector_type(8)));
typedef float floatx4 __attribute__((ext_vector_type(4)));
typedef float f32x4 __attribute__((ext_vector_type(4)));

__device__ __forceinline__ unsigned short f2bf(float f) {
    unsigned u = __builtin_bit_cast(unsigned, f);
    u += 0x7FFFu + ((u >> 16) & 1u);   // round-to-nearest-even
    return (unsigned short)(u >> 16);
}
__device__ __forceinline__ float bf2f(unsigned short b) {
    unsigned u = ((unsigned)b) << 16;
    return __builtin_bit_cast(float, u);
}
// HW packed f32->bf16 (RNE), 2 elems / inst
__device__ __forceinline__ unsigned pkbf(float a, float b) {
    unsigned r;
    asm("v_cvt_pk_bf16_f32 %0, %1, %2" : "=v"(r) : "v"(a), "v"(b));
    return r;
}

// ---------------------------------------------------------------------------
// PREP: blocks 0..383 build swizzled fused weights; block 384 zeroes norms;
// blocks 385..400 per-batch q contributions (+layer-1 biases), exact fp32.
// wswz: flat = ((ct*12+s)*64 + lane)*8 + j <-> B[k=s*32+(lane>>4)*8+j][n=ct*16+(lane&15)]
// ---------------------------------------------------------------------------
__global__ void prep_kernel(const float* __restrict__ q_embs,
                            const float* __restrict__ coin_w1,
                            const float* __restrict__ coin_b1,
                            const float* __restrict__ path_w1,
                            const float* __restrict__ path_b1,
                            unsigned short* __restrict__ wswz,
                            float* __restrict__ qcoin, float* __restrict__ qpath,
                            float* __restrict__ norms) {
    int blk = blockIdx.x;
    int t = threadIdx.x;
    if (blk < 384) {
        int f = blk * 256 + t;                   // 98304 total
        int j  = f & 7;
        int l  = (f >> 3) & 63;
        int ss = (f >> 9) % KSTEPS;
        int ct = f / (KSTEPS * 512);
        int k = ss * 32 + ((l >> 4) << 3) + j;
        int n = ct * 16 + (l & 15);
        float v = (n < H_SZ) ? coin_w1[k * H_SZ + n]
                             : path_w1[k * H_SZ + (n - H_SZ)];
        wswz[f] = f2bf(v);
    } else if (blk == 384) {
        if (t < B_SZ) norms[t] = 0.f;
    } else {
        int b = blk - 385;
        const float* q = q_embs + b * D_SZ;
        if (t < H_SZ) {
            float acc = coin_b1[t];
            for (int d = 0; d < D_SZ; d++)
                acc += q[d] * coin_w1[(D_SZ + d) * H_SZ + t];
            qcoin[b * H_SZ + t] = acc;
        } else if (t < 2 * H_SZ) {
            int h = t - H_SZ;
            float acc = path_b1[h];
            for (int d = 0; d < D_SZ; d++)
                acc += q[d] * path_w1[(D_SZ + K_SZ + d) * H_SZ + h];
            qpath[b * H_SZ + h] = acc;
        }
    }
}

// ---------------------------------------------------------------------------
// GEMM v10 = v7 K-loop (proven best) + nontemporal A loads (stream from HBM,
// don't thrash L3; B stays cached) + split epilogue-C (2x shorter LDS chain).
// 3-chunk (BK=128) software pipeline, double-buffered LDS: per chunk issue
// next chunk's 8 global float4 loads EARLY, MFMA current buffer, cvt+ds_write
// arrived data, one barrier.
// ---------------------------------------------------------------------------
__global__ __launch_bounds__(256)
void gemm_fused(const float* __restrict__ sent,
                const unsigned short* __restrict__ wswz,
                const float* __restrict__ qcoin,
                const float* __restrict__ coin_w2,
                const float* __restrict__ coin_b2,
                unsigned short* __restrict__ hpathB,
                float* __restrict__ amps) {
    __shared__ __align__(16) short als[2 * 64 * LDSB_STRIDE];  // 36864 B
    __shared__ __align__(16) float w2s[H_SZ * K_SZ];           // 4096 B -> 40960 total
    short* buf0 = als;
    short* buf1 = als + 64 * LDSB_STRIDE;
    const int tid = threadIdx.x;
    const int wave = tid >> 6, lane = tid & 63;
    const int m_lane = lane & 15, quad = lane >> 4;
    const int mt = blockIdx.x;                   // 2048 blocks, one tile each
    const int b = mt >> 7;                       // batch (8192 rows / batch)
    const float* abase = sent + (size_t)mt * 64 * D_SZ;
    const int row8 = tid >> 5;                   // e4 = u*256+tid: row = row8 + u*8
    const int c4   = tid & 31;                   // 32 float4 per chunk-row

    // w2s staging overlaps the pipeline (own array; barriers below order it)
    for (int i = tid; i < H_SZ * K_SZ; i += 256) w2s[i] = coin_w2[i];

    const unsigned short* wbase = wswz + (size_t)wave * 4 * KSTEPS * 512 + lane * 8;
    floatx4 acc[4][4];
#pragma unroll
    for (int rt = 0; rt < 4; rt++)
#pragma unroll
        for (int c = 0; c < 4; c++) acc[rt][c] = (floatx4){0.f, 0.f, 0.f, 0.f};

    f32x4 v[8];

#define STAGE_LOAD(CHUNK)                                                        \
    _Pragma("unroll")                                                            \
    for (int u = 0; u < 8; u++)                                                  \
        v[u] = __builtin_nontemporal_load(                                       \
            (const f32x4*)(abase + (size_t)(row8 + u * 8) * D_SZ +               \
                           (CHUNK) * CK + c4 * 4));

#define STAGE_STORE(BUF)                                                         \
    _Pragma("unroll")                                                            \
    for (int u = 0; u < 8; u++) {                                                \
        int2 p;                                                                  \
        p.x = (int)pkbf(v[u].x, v[u].y);                                         \
        p.y = (int)pkbf(v[u].z, v[u].w);                                         \
        *(int2*)&(BUF)[(row8 + u * 8) * LDSB_STRIDE + c4 * 4] = p;               \
    }

#define MMA_CHUNK(BUF, CHUNK)                                                    \
    _Pragma("unroll")                                                            \
    for (int sl = 0; sl < 4; sl++) {                                             \
        const int s = (CHUNK) * 4 + sl;                                          \
        short8 bfr[4];                                                           \
        _Pragma("unroll")                                                        \
        for (int cc = 0; cc < 4; cc++)                                           \
            bfr[cc] = *(const short8*)(wbase + (size_t)(cc * KSTEPS + s) * 512); \
        short8 af[4];                                                            \
        _Pragma("unroll")                                                        \
        for (int rt = 0; rt < 4; rt++)                                           \
            af[rt] = *(const short8*)&(BUF)[(rt * 16 + m_lane) * LDSB_STRIDE +   \
                                            sl * 32 + quad * 8];                 \
        _Pragma("unroll")                                                        \
        for (int rt = 0; rt < 4; rt++)                                           \
            _Pragma("unroll")                                                    \
            for (int cc = 0; cc < 4; cc++)                                       \
                acc[rt][cc] = __builtin_amdgcn_mfma_f32_16x16x32_bf16(           \
                    af[rt], bfr[cc], acc[rt][cc], 0, 0, 0);                      \
    }

    // prologue: chunk 0
    STAGE_LOAD(0);
    STAGE_STORE(buf0);
    __syncthreads();
    // chunk 0 compute || chunk 1 loads in flight
    STAGE_LOAD(1);
    MMA_CHUNK(buf0, 0);
    STAGE_STORE(buf1);
    __syncthreads();
    // chunk 1 compute || chunk 2 loads in flight
    STAGE_LOAD(2);
    MMA_CHUNK(buf1, 1);
    STAGE_STORE(buf0);
    __syncthreads();
    // chunk 2 compute
    MMA_CHUNK(buf0, 2);

    // ---- epilogue A: path waves store blocked int2 bf16 h (register-only) ----
    if (wave >= 2) {
        const int colw = (wave & 1) * 64;
#pragma unroll
        for (int rt = 0; rt < 4; rt++) {
            int mt16 = mt * 4 + rt;
#pragma unroll
            for (int c = 0; c < 4; c++) {
                int col = colw + c * 16 + m_lane;
                int2 p;
                p.x = (int)pkbf(acc[rt][c][0], acc[rt][c][1]);
                p.y = (int)pkbf(acc[rt][c][2], acc[rt][c][3]);
                *(int2*)(hpathB + (size_t)mt16 * 2048 + col * 16 + quad * 4) = p;
            }
        }
    }
    __syncthreads();                             // all LDS reads done -> reuse als

    // ---- epilogue B: coin waves -> relu(h + qcoin) into LDS (f32) ----
    float* hs = (float*)als;                     // 64 x 130 f32 = 33280 B <= 36864
    if (wave < 2) {
        const int colw = wave * 64;
        float qc[4];
#pragma unroll
        for (int c = 0; c < 4; c++)
            qc[c] = qcoin[b * H_SZ + colw + c * 16 + m_lane];
#pragma unroll
        for (int rt = 0; rt < 4; rt++)
#pragma unroll
            for (int c = 0; c < 4; c++) {
                int colj = colw + c * 16 + m_lane;
#pragma unroll
                for (int j = 0; j < 4; j++) {
                    int row = rt * 16 + quad * 4 + j;
                    float hv = acc[rt][c][j] + qc[c];
                    hs[row * HS_STRIDE + colj] = hv > 0.f ? hv : 0.f;
                }
            }
    }
    __syncthreads();

    // ---- epilogue C (split): thread = (row, k-quad, c-half); shfl-combine ----
    {
        const int r  = tid >> 2;                 // 0..63 row in tile
        const int kp = (tid >> 1) & 1;           // k-quad: k = kp*4..kp*4+3
        const int hf = tid & 1;                  // c-half: c = hf*64..hf*64+63
        float4 a4 = (hf == 0) ? *(const float4*)(coin_b2 + kp * 4)
                              : make_float4(0.f, 0.f, 0.f, 0.f);
        const float* hrow = hs + r * HS_STRIDE + hf * 64;
        const float* wb   = w2s + hf * 512 + kp * 4;
#pragma unroll 16
        for (int c = 0; c < 64; c++) {
            float hv = hrow[c];
            float4 w = *(const float4*)(wb + c * 8);
            a4.x += hv * w.x; a4.y += hv * w.y; a4.z += hv * w.z; a4.w += hv * w.w;
        }
        a4.x += __shfl_xor(a4.x, 1);
        a4.y += __shfl_xor(a4.y, 1);
        a4.z += __shfl_xor(a4.z, 1);
        a4.w += __shfl_xor(a4.w, 1);
        if (hf == 0) {
            const size_t m = (size_t)mt * 64 + r;
            *(float4*)(amps + m * 8 + kp * 4) = a4;
        }
    }
#undef STAGE_LOAD
#undef STAGE_STORE
#undef MMA_CHUNK
}

// ---------------------------------------------------------------------------
// walk_fused: one block per (batch b, coin k) slice — 128 blocks x 1024 thr.
// Slice state (8192 f32 = 32 KB) double-buffered in LDS; all 3 steps with
// plain __syncthreads(). amps in registers; z never round-trips HBM.
// ---------------------------------------------------------------------------
__global__ __launch_bounds__(1024)
void walk_fused(const float* __restrict__ amps,
                const int* __restrict__ neighbors,
                float* __restrict__ zfinal,
                float* __restrict__ norms) {
    __shared__ float z0buf[N_SZ];    // 32 KB
    __shared__ float z1buf[N_SZ];    // 32 KB
    __shared__ float bsum;
    const int tid = threadIdx.x;
    const int b = blockIdx.x >> 3;
    const int k = blockIdx.x & 7;
    const size_t nodebase = (size_t)b * N_SZ;

    float a[8];
#pragma unroll
    for (int u = 0; u < 8; u++) {
        int n = u * 1024 + tid;
        a[u] = amps[(nodebase + n) * 8 + k];
        z0buf[n] = a[u] * (1.0f / 256.0f);       // exact pow2 fold of z0
    }
    if (tid == 0) bsum = 0.f;
    __syncthreads();

    float* zc = z0buf;
    float* zn = z1buf;
    float ss = 0.f;
#pragma unroll
    for (int step = 0; step < 3; step++) {
#pragma unroll
        for (int u = 0; u < 8; u++) {
            const int n = u * 1024 + tid;
            const int4* nb4 = (const int4*)(neighbors + (nodebase + n) * KN_SZ);
            int4 q0 = nb4[0], q1 = nb4[1], q2 = nb4[2], q3 = nb4[3];
            float v = zc[n];
            int idx[16] = {q0.x, q0.y, q0.z, q0.w, q1.x, q1.y, q1.z, q1.w,
                           q2.x, q2.y, q2.z, q2.w, q3.x, q3.y, q3.z, q3.w};
#pragma unroll
            for (int i = 0; i < 16; i++) {
                int nn = idx[i];
                if ((unsigned)nn < (unsigned)N_SZ) v += zc[nn];
            }
            if (step < 2) v *= a[u];
            zn[n] = v;
            if (step == 2) ss += v * v;
        }
        __syncthreads();
        float* t = zc; zc = zn; zn = t;
    }

#pragma unroll
    for (int o = 32; o > 0; o >>= 1) ss += __shfl_down(ss, o);
    if ((tid & 63) == 0) atomicAdd(&bsum, ss);
    __syncthreads();
    if (tid == 0) atomicAdd(&norms[b], bsum);

#pragma unroll
    for (int u = 0; u < 8; u++) {
        int n = u * 1024 + tid;
        zfinal[(nodebase + n) * 8 + k] = zc[n];
    }
}

// ---------------------------------------------------------------------------
// logits v3: 4 threads per node (seg = tid&3 owns 32 h's), reads the BLOCKED
// hpathB layout coalesced. Seg-padded LDS weight layouts conflict-free.
// ---------------------------------------------------------------------------
__global__ __launch_bounds__(256)
void logits_kernel(const unsigned short* __restrict__ hpathB,
                   const float* __restrict__ qpath,
                   const float* __restrict__ u2,
                   const float* __restrict__ norms,
                   const float* __restrict__ path_w1,
                   const float* __restrict__ path_w2,
                   const float* __restrict__ path_b2,
                   float* __restrict__ out) {
    __shared__ float w1t[4 * 260];   // seg*260 + i*8 + j
    __shared__ float w2sp[4 * 33];   // seg*33 + i
    __shared__ float qps[4 * 33];
    const int tid = threadIdx.x;
    const int mbase = blockIdx.x * 64;           // 64 nodes / block, 2048 blocks
    const int b = mbase >> 13;                   // block-uniform (128 blocks/batch)
    for (int i2 = tid; i2 < H_SZ * K_SZ; i2 += 256) {
        int h = i2 >> 3, j = i2 & 7;
        w1t[(h >> 5) * 260 + (h & 31) * 8 + j] = path_w1[(D_SZ + j) * H_SZ + h];
    }
    if (tid < H_SZ) {
        int idx = (tid >> 5) * 33 + (tid & 31);
        w2sp[idx] = path_w2[tid];
        qps[idx]  = qpath[b * H_SZ + tid];
    }
    __syncthreads();

    const int m = mbase + (tid >> 2);
    const int seg = tid & 3;
    float ssq = norms[b];
    float inv = ssq > 0.f ? rsqrtf(ssq) : 1.0f;
    float st[K_SZ];
    {
        float4 s0 = *(const float4*)(u2 + (size_t)m * 8);
        float4 s1 = *(const float4*)(u2 + (size_t)m * 8 + 4);
        st[0] = s0.x * inv; st[1] = s0.y * inv; st[2] = s0.z * inv; st[3] = s0.w * inv;
        st[4] = s1.x * inv; st[5] = s1.y * inv; st[6] = s1.z * inv; st[7] = s1.w * inv;
    }
    const unsigned short* hb = hpathB + (size_t)(m >> 4) * 2048 + (m & 15);
    const float* w1b = &w1t[seg * 260];
    const float* w2b = &w2sp[seg * 33];
    const float* qpb = &qps[seg * 33];
    const int hseg = seg * 32;

    float acc = 0.f;
#pragma unroll 8
    for (int i = 0; i < 32; i++) {
        float hv = bf2f(hb[(hseg + i) * 16]) + qpb[i];
        float4 wa = *(const float4*)&w1b[i * 8];
        float4 wb = *(const float4*)&w1b[i * 8 + 4];
        hv += st[0]*wa.x + st[1]*wa.y + st[2]*wa.z + st[3]*wa.w
            + st[4]*wb.x + st[5]*wb.y + st[6]*wb.z + st[7]*wb.w;
        hv = hv > 0.f ? hv : 0.f;
        acc += hv * w2b[i];
    }
    acc += __shfl_xor(acc, 1);
    acc += __shfl_xor(acc, 2);
    if (seg == 0) out[m] = acc + path_b2[0];
}

// ---------------------------------------------------------------------------
extern "C" void kernel_launch(void* const* d_in, const int* in_sizes, int n_in,
                              void* d_out, int out_size, void* d_ws, size_t ws_size,
                              hipStream_t stream) {
    const float* sent      = (const float*)d_in[0];
    const float* q_embs    = (const float*)d_in[1];
    const int*   neighbors = (const int*)d_in[2];
    const float* coin_w1   = (const float*)d_in[3];
    const float* coin_b1   = (const float*)d_in[4];
    const float* coin_w2   = (const float*)d_in[5];
    const float* coin_b2   = (const float*)d_in[6];
    const float* path_w1   = (const float*)d_in[7];
    const float* path_b1   = (const float*)d_in[8];
    const float* path_w2   = (const float*)d_in[9];
    const float* path_b2   = (const float*)d_in[10];
    float* out = (float*)d_out;

    char* ws = (char*)d_ws;
    unsigned short* wswz = (unsigned short*)ws;                   // 196608 B
    float* qcoin = (float*)(ws + 196608);                         // 8192 B
    float* qpath = (float*)(ws + 204800);                         // 8192 B
    float* norms = (float*)(ws + 212992);                         // 256 B
    unsigned short* hpathB = (unsigned short*)(ws + 213248);      // 33554432 B
    float* amps = (float*)(ws + 33767680);                        // 4 MB
    float* zB   = (float*)(ws + 37961984);                        // 4 MB

    prep_kernel<<<401, 256, 0, stream>>>(q_embs, coin_w1, coin_b1, path_w1, path_b1,
                                         wswz, qcoin, qpath, norms);
    gemm_fused<<<MT64, 256, 0, stream>>>(sent, wswz, qcoin, coin_w2, coin_b2,
                                         hpathB, amps);
    walk_fused<<<B_SZ * K_SZ, 1024, 0, stream>>>(amps, neighbors, zB, norms);
    logits_kernel<<<M_TOTAL / 64, 256, 0, stream>>>(hpathB, qpath, zB, norms,
                                                    path_w1, path_w2, path_b2, out);
}